// Round 12
// baseline (183.250 us; speedup 1.0000x reference)
//
#include <hip/hip_runtime.h>
#include <stdint.h>

#define V_DIM 32000
#define M_TOT 4096      // B*S
#define NF 128          // 2*n_freq
#define NC 256          // channels
#define BM 64           // M-tile (64 mt tiles)
#define BK 32
#define KSTEPS 1000     // V_DIM / BK
#define NSPL 16
#define ASTR 66         // A slot stride per kg-plane (slots of 16B): +8 bank rotation
#define BSTR 130        // B slot stride per kg-plane: +8 bank rotation
#define THREADS 256

typedef __bf16 bf16x8 __attribute__((ext_vector_type(8)));
typedef float f32x4 __attribute__((ext_vector_type(4)));
typedef float fvec4 __attribute__((ext_vector_type(4)));

__device__ __forceinline__ unsigned short f2bf(float f) {  // RNE
  unsigned int u = __float_as_uint(f);
  u += 0x7FFFu + ((u >> 16) & 1u);
  return (unsigned short)(u >> 16);
}

// Non-temporal x load: stream without polluting L2/L3 (keep T resident there).
__device__ __forceinline__ fvec4 ntload4(const float* p) {
  return __builtin_nontemporal_load(reinterpret_cast<const fvec4*>(p));
}

__device__ __forceinline__ int4 pack8(fvec4 lo, fvec4 hi) {
  union { unsigned short us[8]; int4 v; } u;
  u.us[0] = f2bf(lo[0]); u.us[1] = f2bf(lo[1]);
  u.us[2] = f2bf(lo[2]); u.us[3] = f2bf(lo[3]);
  u.us[4] = f2bf(hi[0]); u.us[5] = f2bf(hi[1]);
  u.us[6] = f2bf(hi[2]); u.us[7] = f2bf(hi[3]);
  return u.v;
}

// ---------------- Stage 0: DFT basis table in THREAD-STAGING order ----------------
// T_stage[c][q*256 + t] = 8 bf16; element e -> T_logical[row][c*32 + kg*8 + e]
//   row = (t>>2) + 64*q, kg = t&3
//   T_logical[f][v] = cos(2pi(f+1)v/V) f<64 ; -sin(2pi(f-63)v/V) f>=64
__global__ __launch_bounds__(256) void build_table(unsigned short* __restrict__ T) {
  int id = blockIdx.x * 256 + threadIdx.x;        // slot id, 512 per chunk
  if (id >= 512 * KSTEPS) return;                 // 512000
  int c = id >> 9;
  int r = id & 511;
  int q = r >> 8;
  int tt = r & 255;
  int row = (tt >> 2) + 64 * q;
  int kg = tt & 3;
  int k = (row < 64) ? (row + 1) : (row - 63);
  bool is_cos = (row < 64);
  int vb = c * 32 + kg * 8;
  const float w0 = 6.283185307179586f / (float)V_DIM;
  union { unsigned short us[8]; int4 v; } u;
  #pragma unroll
  for (int e = 0; e < 8; ++e) {
    int m = (k * (vb + e)) % V_DIM;               // exact range reduction
    float s, cc;
    __sincosf((float)m * w0, &s, &cc);
    u.us[e] = f2bf(is_cos ? cc : -s);
  }
  *reinterpret_cast<int4*>(T + (size_t)id * 8) = u.v;
}

// ---------------- Stage 1: P[ks] = x_tile @ T_chunk^T ----------------
// R5-proven schedule (159 us), single change: x loads are NON-TEMPORAL.
__global__ __launch_bounds__(THREADS) void gemm1(
    const float* __restrict__ x, const unsigned short* __restrict__ T,
    float* __restrict__ P) {
  __shared__ __align__(16) unsigned short As[2][4 * ASTR * 8];  // 4224 B / buf
  __shared__ __align__(16) unsigned short Bs[2][4 * BSTR * 8];  // 8320 B / buf

  // XCD j (b&7) hosts only ks in {j, j+8} -> ~1MB of T per XCD L2
  const int b = blockIdx.x;
  const int j = b & 7, i = b >> 3;      // i: 0..127
  const int ks = j + 8 * (i & 1);
  const int mt = i >> 1;                // 0..63
  const int m0 = mt * BM;

  const int basek = KSTEPS / NSPL, remk = KSTEPS % NSPL;  // 62, 8
  const int steps = basek + (ks < remk);
  const int start = ks * basek + (ks < remk ? ks : remk);

  const int t = threadIdx.x;
  const int lane = t & 63, wave = t >> 6;
  const int wm = wave >> 1, wn = wave & 1;   // wave tile 32m x 64n
  const int kgl = lane >> 4, rl = lane & 15;

  const int kg_t = t & 3;
  const int row_t = t >> 2;                  // 0..63 (one A slot per thread)
  const int aslot = kg_t * ASTR + row_t;
  const int bslot0 = kg_t * BSTR + row_t;    // staged slot (kg,row)
  const int bslot1 = bslot0 + 64;            // (kg, row+64)

  const float* xa = x + (size_t)(m0 + row_t) * V_DIM + kg_t * 8 + (size_t)start * BK;
  const unsigned short* Tc = T + (size_t)start * 4096;

  f32x4 acc[2][4];
  #pragma unroll
  for (int a = 0; a < 2; ++a)
    #pragma unroll
    for (int c = 0; c < 4; ++c) acc[a][c] = (f32x4){0.f, 0.f, 0.f, 0.f};

  // ---- prologue: stage step 0 into buf0
  {
    fvec4 a0 = ntload4(xa);
    fvec4 a1 = ntload4(xa + 4);
    int4 b0 = *reinterpret_cast<const int4*>(Tc + t * 8);
    int4 b1 = *reinterpret_cast<const int4*>(Tc + (256 + t) * 8);
    *reinterpret_cast<int4*>(&As[0][aslot * 8]) = pack8(a0, a1);
    *reinterpret_cast<int4*>(&Bs[0][bslot0 * 8]) = b0;
    *reinterpret_cast<int4*>(&Bs[0][bslot1 * 8]) = b1;
    __syncthreads();
  }

  for (int s = 0; s < steps; ++s) {
    const int cur = s & 1, nxt = cur ^ 1;
    const bool pre = (s + 1 < steps);

    // 1) issue next step's 4 global loads first (latency overlapped by MFMAs)
    fvec4 a0, a1;
    int4 b0, b1;
    if (pre) {
      const float* xp = xa + (size_t)(s + 1) * BK;
      a0 = ntload4(xp);
      a1 = ntload4(xp + 4);
      const unsigned short* tc = Tc + (size_t)(s + 1) * 4096;
      b0 = *reinterpret_cast<const int4*>(tc + t * 8);
      b1 = *reinterpret_cast<const int4*>(tc + (256 + t) * 8);
    }

    // 2) fragments + MFMA on current buffer
    bf16x8 bv[4];
    #pragma unroll
    for (int nf = 0; nf < 4; ++nf)
      bv[nf] = *reinterpret_cast<const bf16x8*>(
          &Bs[cur][(kgl * BSTR + wn * 64 + nf * 16 + rl) * 8]);
    #pragma unroll
    for (int mf = 0; mf < 2; ++mf) {
      bf16x8 av = *reinterpret_cast<const bf16x8*>(
          &As[cur][(kgl * ASTR + wm * 32 + mf * 16 + rl) * 8]);
      #pragma unroll
      for (int nf = 0; nf < 4; ++nf)
        acc[mf][nf] = __builtin_amdgcn_mfma_f32_16x16x32_bf16(
            av, bv[nf], acc[mf][nf], 0, 0, 0);
    }

    // 3) consume loads mid-step (vmcnt wait covered by MFMA issue above)
    if (pre) {
      *reinterpret_cast<int4*>(&As[nxt][aslot * 8]) = pack8(a0, a1);
      *reinterpret_cast<int4*>(&Bs[nxt][bslot0 * 8]) = b0;
      *reinterpret_cast<int4*>(&Bs[nxt][bslot1 * 8]) = b1;
    }
    __syncthreads();
  }

  // ---- epilogue: partial [64 x 128] tile for this k-split
  float* Pp = P + ((size_t)ks * M_TOT + m0) * NF;
  const int r0 = (lane >> 4) * 4;
  const int col = lane & 15;
  #pragma unroll
  for (int mf = 0; mf < 2; ++mf)
    #pragma unroll
    for (int nf = 0; nf < 4; ++nf)
      #pragma unroll
      for (int q = 0; q < 4; ++q) {
        int row = wm * 32 + mf * 16 + r0 + q;
        int n = wn * 64 + nf * 16 + col;
        Pp[(size_t)row * NF + n] = acc[mf][nf][q];
      }
}

// ---------------- Stage 2: out = (sum_s P[s]) @ W^T ----------------
__global__ __launch_bounds__(256) void gemm2(
    const float* __restrict__ P, const float* __restrict__ W,
    float* __restrict__ out, int NS) {
  __shared__ __align__(16) float Xr[8][NF];
  const int mb = blockIdx.x * 8;
  const int t = threadIdx.x;

  #pragma unroll
  for (int i = 0; i < 4; ++i) {
    int idx = t + i * 256;           // 8 rows x 128 freqs
    int r = idx >> 7, f = idx & 127;
    float s = 0.f;
    for (int sp = 0; sp < NS; ++sp)
      s += P[((size_t)sp * M_TOT + mb + r) * NF + f];
    Xr[r][f] = s;
  }
  __syncthreads();

  const float4* Wr = reinterpret_cast<const float4*>(W + (size_t)t * NF);
  float accr[8];
  #pragma unroll
  for (int r = 0; r < 8; ++r) accr[r] = 0.f;

  for (int f4 = 0; f4 < NF / 4; ++f4) {
    float4 w = Wr[f4];
    #pragma unroll
    for (int r = 0; r < 8; ++r) {
      float4 xv = *reinterpret_cast<const float4*>(&Xr[r][f4 * 4]);
      accr[r] += xv.x * w.x + xv.y * w.y + xv.z * w.z + xv.w * w.w;
    }
  }
  #pragma unroll
  for (int r = 0; r < 8; ++r)
    out[(size_t)(mb + r) * NC + t] = accr[r];
}

extern "C" void kernel_launch(void* const* d_in, const int* in_sizes, int n_in,
                              void* d_out, int out_size, void* d_ws, size_t ws_size,
                              hipStream_t stream) {
  const float* x = (const float*)d_in[0];
  const float* w = (const float*)d_in[1];
  float* out = (float*)d_out;

  unsigned short* T = (unsigned short*)d_ws;
  const size_t t_bytes = (size_t)NF * V_DIM * sizeof(unsigned short); // 8,192,000
  float* P = (float*)((char*)d_ws + t_bytes);
  // ws need: 8 MB (T) + 32 MB (P) = 40 MB (proven available).

  build_table<<<dim3(2000), dim3(256), 0, stream>>>(T);
  gemm1<<<dim3(64 * NSPL), dim3(THREADS), 0, stream>>>(x, T, P);
  gemm2<<<dim3(M_TOT / 8), dim3(256), 0, stream>>>(P, w, out, NSPL);
}

// Round 13
// 146.965 us; speedup vs baseline: 1.2469x; 1.2469x over previous
//
#include <hip/hip_runtime.h>
#include <stdint.h>

#define V_DIM 32000
#define M_TOT 4096      // B*S
#define NF 128          // 2*n_freq
#define NC 256          // channels
#define BM 64           // M-tile (64 mt tiles)
#define BK 32
#define KSTEPS 1000     // V_DIM / BK
#define NSPL 16
#define ASTR 66         // A slot stride per kg-plane (slots of 16B): +8 bank rotation
#define BSTR 130        // B slot stride per kg-plane: +8 bank rotation
#define THREADS 256

typedef __bf16 bf16x8 __attribute__((ext_vector_type(8)));
typedef float f32x4 __attribute__((ext_vector_type(4)));

__device__ __forceinline__ unsigned short f2bf(float f) {  // RNE
  unsigned int u = __float_as_uint(f);
  u += 0x7FFFu + ((u >> 16) & 1u);
  return (unsigned short)(u >> 16);
}

__device__ __forceinline__ float bf2f(unsigned short h) {
  unsigned int u = (unsigned int)h << 16;
  return __uint_as_float(u);
}

__device__ __forceinline__ int4 pack8(float4 lo, float4 hi) {
  union { unsigned short us[8]; int4 v; } u;
  u.us[0] = f2bf(lo.x); u.us[1] = f2bf(lo.y);
  u.us[2] = f2bf(lo.z); u.us[3] = f2bf(lo.w);
  u.us[4] = f2bf(hi.x); u.us[5] = f2bf(hi.y);
  u.us[6] = f2bf(hi.z); u.us[7] = f2bf(hi.w);
  return u.v;
}

// ---------------- Stage 0: DFT basis table in THREAD-STAGING order ----------------
// T_stage[c][q*256 + t] = 8 bf16; element e -> T_logical[row][c*32 + kg*8 + e]
//   row = (t>>2) + 64*q, kg = t&3
//   T_logical[f][v] = cos(2pi(f+1)v/V) f<64 ; -sin(2pi(f-63)v/V) f>=64
__global__ __launch_bounds__(256) void build_table(unsigned short* __restrict__ T) {
  int id = blockIdx.x * 256 + threadIdx.x;        // slot id, 512 per chunk
  if (id >= 512 * KSTEPS) return;                 // 512000
  int c = id >> 9;
  int r = id & 511;
  int q = r >> 8;
  int tt = r & 255;
  int row = (tt >> 2) + 64 * q;
  int kg = tt & 3;
  int k = (row < 64) ? (row + 1) : (row - 63);
  bool is_cos = (row < 64);
  int vb = c * 32 + kg * 8;
  const float w0 = 6.283185307179586f / (float)V_DIM;
  union { unsigned short us[8]; int4 v; } u;
  #pragma unroll
  for (int e = 0; e < 8; ++e) {
    int m = (k * (vb + e)) % V_DIM;               // exact range reduction
    float s, cc;
    __sincosf((float)m * w0, &s, &cc);
    u.us[e] = f2bf(is_cos ? cc : -s);
  }
  *reinterpret_cast<int4*>(T + (size_t)id * 8) = u.v;
}

// ---------------- Stage 1: P[ks] = x_tile @ T_chunk^T (P stored bf16) ---------------
// Schedule byte-identical to R5 (159us best): loads at top, consumed mid-step,
// one barrier per step. Only the epilogue (bf16 P) differs.
__global__ __launch_bounds__(THREADS) void gemm1(
    const float* __restrict__ x, const unsigned short* __restrict__ T,
    unsigned short* __restrict__ P) {
  __shared__ __align__(16) unsigned short As[2][4 * ASTR * 8];  // 4224 B / buf
  __shared__ __align__(16) unsigned short Bs[2][4 * BSTR * 8];  // 8320 B / buf

  // XCD j (b&7) hosts only ks in {j, j+8} -> ~1MB of T per XCD L2
  const int b = blockIdx.x;
  const int j = b & 7, i = b >> 3;      // i: 0..127
  const int ks = j + 8 * (i & 1);
  const int mt = i >> 1;                // 0..63
  const int m0 = mt * BM;

  const int basek = KSTEPS / NSPL, remk = KSTEPS % NSPL;  // 62, 8
  const int steps = basek + (ks < remk);
  const int start = ks * basek + (ks < remk ? ks : remk);

  const int t = threadIdx.x;
  const int lane = t & 63, wave = t >> 6;
  const int wm = wave >> 1, wn = wave & 1;   // wave tile 32m x 64n
  const int kgl = lane >> 4, rl = lane & 15;

  const int kg_t = t & 3;
  const int row_t = t >> 2;                  // 0..63 (one A slot per thread)
  const int aslot = kg_t * ASTR + row_t;
  const int bslot0 = kg_t * BSTR + row_t;    // staged slot (kg,row)
  const int bslot1 = bslot0 + 64;            // (kg, row+64)

  const float* xa = x + (size_t)(m0 + row_t) * V_DIM + kg_t * 8 + (size_t)start * BK;
  const unsigned short* Tc = T + (size_t)start * 4096;

  f32x4 acc[2][4];
  #pragma unroll
  for (int a = 0; a < 2; ++a)
    #pragma unroll
    for (int c = 0; c < 4; ++c) acc[a][c] = (f32x4){0.f, 0.f, 0.f, 0.f};

  // ---- prologue: stage step 0 into buf0
  {
    float4 a0 = *reinterpret_cast<const float4*>(xa);
    float4 a1 = *reinterpret_cast<const float4*>(xa + 4);
    int4 b0 = *reinterpret_cast<const int4*>(Tc + t * 8);
    int4 b1 = *reinterpret_cast<const int4*>(Tc + (256 + t) * 8);
    *reinterpret_cast<int4*>(&As[0][aslot * 8]) = pack8(a0, a1);
    *reinterpret_cast<int4*>(&Bs[0][bslot0 * 8]) = b0;
    *reinterpret_cast<int4*>(&Bs[0][bslot1 * 8]) = b1;
    __syncthreads();
  }

  for (int s = 0; s < steps; ++s) {
    const int cur = s & 1, nxt = cur ^ 1;
    const bool pre = (s + 1 < steps);

    // 1) issue next step's 4 global loads first (latency overlapped by MFMAs)
    float4 a0, a1;
    int4 b0, b1;
    if (pre) {
      const float* xp = xa + (size_t)(s + 1) * BK;
      a0 = *reinterpret_cast<const float4*>(xp);
      a1 = *reinterpret_cast<const float4*>(xp + 4);
      const unsigned short* tc = Tc + (size_t)(s + 1) * 4096;
      b0 = *reinterpret_cast<const int4*>(tc + t * 8);
      b1 = *reinterpret_cast<const int4*>(tc + (256 + t) * 8);
    }

    // 2) fragments + MFMA on current buffer
    bf16x8 bv[4];
    #pragma unroll
    for (int nf = 0; nf < 4; ++nf)
      bv[nf] = *reinterpret_cast<const bf16x8*>(
          &Bs[cur][(kgl * BSTR + wn * 64 + nf * 16 + rl) * 8]);
    #pragma unroll
    for (int mf = 0; mf < 2; ++mf) {
      bf16x8 av = *reinterpret_cast<const bf16x8*>(
          &As[cur][(kgl * ASTR + wm * 32 + mf * 16 + rl) * 8]);
      #pragma unroll
      for (int nf = 0; nf < 4; ++nf)
        acc[mf][nf] = __builtin_amdgcn_mfma_f32_16x16x32_bf16(
            av, bv[nf], acc[mf][nf], 0, 0, 0);
    }

    // 3) consume loads mid-step (vmcnt wait covered by MFMA issue above)
    if (pre) {
      *reinterpret_cast<int4*>(&As[nxt][aslot * 8]) = pack8(a0, a1);
      *reinterpret_cast<int4*>(&Bs[nxt][bslot0 * 8]) = b0;
      *reinterpret_cast<int4*>(&Bs[nxt][bslot1 * 8]) = b1;
    }
    __syncthreads();
  }

  // ---- epilogue: partial [64 x 128] tile, bf16 (halves P traffic)
  unsigned short* Pp = P + ((size_t)ks * M_TOT + m0) * NF;
  const int r0 = (lane >> 4) * 4;
  const int col = lane & 15;
  #pragma unroll
  for (int mf = 0; mf < 2; ++mf)
    #pragma unroll
    for (int nf = 0; nf < 4; ++nf)
      #pragma unroll
      for (int q = 0; q < 4; ++q) {
        int row = wm * 32 + mf * 16 + r0 + q;
        int n = wn * 64 + nf * 16 + col;
        Pp[(size_t)row * NF + n] = f2bf(acc[mf][nf][q]);
      }
}

// ---------------- Stage 2: out = (sum_s P[s]) @ W^T  (P is bf16) ----------------
__global__ __launch_bounds__(256) void gemm2(
    const unsigned short* __restrict__ P, const float* __restrict__ W,
    float* __restrict__ out, int NS) {
  __shared__ __align__(16) float Xr[8][NF];
  const int mb = blockIdx.x * 8;
  const int t = threadIdx.x;

  // 256 threads cover 8 rows x 32 freq-quads exactly: each sums NS ushort4 loads
  {
    const int r = t >> 5, fq = t & 31;          // row 0..7, quad 0..31
    float s0 = 0.f, s1 = 0.f, s2 = 0.f, s3 = 0.f;
    const unsigned short* p = P + ((size_t)(mb + r)) * NF + fq * 4;
    for (int sp = 0; sp < NS; ++sp) {
      ushort4 v = *reinterpret_cast<const ushort4*>(p + (size_t)sp * M_TOT * NF);
      s0 += bf2f(v.x); s1 += bf2f(v.y); s2 += bf2f(v.z); s3 += bf2f(v.w);
    }
    Xr[r][fq * 4 + 0] = s0; Xr[r][fq * 4 + 1] = s1;
    Xr[r][fq * 4 + 2] = s2; Xr[r][fq * 4 + 3] = s3;
  }
  __syncthreads();

  const float4* Wr = reinterpret_cast<const float4*>(W + (size_t)t * NF);
  float accr[8];
  #pragma unroll
  for (int r = 0; r < 8; ++r) accr[r] = 0.f;

  for (int f4 = 0; f4 < NF / 4; ++f4) {
    float4 w = Wr[f4];
    #pragma unroll
    for (int r = 0; r < 8; ++r) {
      float4 xv = *reinterpret_cast<const float4*>(&Xr[r][f4 * 4]);
      accr[r] += xv.x * w.x + xv.y * w.y + xv.z * w.z + xv.w * w.w;
    }
  }
  #pragma unroll
  for (int r = 0; r < 8; ++r)
    out[(size_t)(mb + r) * NC + t] = accr[r];
}

extern "C" void kernel_launch(void* const* d_in, const int* in_sizes, int n_in,
                              void* d_out, int out_size, void* d_ws, size_t ws_size,
                              hipStream_t stream) {
  const float* x = (const float*)d_in[0];
  const float* w = (const float*)d_in[1];
  float* out = (float*)d_out;

  unsigned short* T = (unsigned short*)d_ws;
  const size_t t_bytes = (size_t)NF * V_DIM * sizeof(unsigned short); // 8,192,000
  unsigned short* P = (unsigned short*)((char*)d_ws + t_bytes);
  // ws need: 8 MB (T) + 16 MB (bf16 P) = 24 MB (proven available).

  build_table<<<dim3(2000), dim3(256), 0, stream>>>(T);
  gemm1<<<dim3(64 * NSPL), dim3(THREADS), 0, stream>>>(x, T, P);
  gemm2<<<dim3(M_TOT / 8), dim3(256), 0, stream>>>(P, w, out, NSPL);
}